// Round 2
// baseline (178.838 us; speedup 1.0000x reference)
//
#include <hip/hip_runtime.h>

// MinEuclideanDistBlock: x(32,8,4096) f32, shapelets(8,128,64) f32 -> out(32,1,128) f32
// out[b,k] = min_w sum_c sqrt( xnorm[b,c,w] + snorm[c,k] - 2*sum_s x[b,c,w+s]*h[c,k,s] )
//
// Design:
//  - cross terms via bf16 MFMA 16x16x32 (M=windows, N=shapelets, K=s), fp32 norms.
//  - (-2) folded into staged bf16 shapelets; MFMA C-operand initialized with
//    xnorm+snorm so acc == d2 directly -> epilogue is just sqrt + accumulate.
//  - x staged in LDS as 8 shifted bf16 rows (Xr[r][j] = x_bf[j+r]) so each
//    A-fragment (8 consecutive s per lane) is one aligned ds_read_b128.
//  - min over w: in-lane -> shfl_xor(16,32) -> uint atomicMin (positive floats).

typedef short short8 __attribute__((ext_vector_type(8)));
typedef float f32x4 __attribute__((ext_vector_type(4)));

constexpr int Bn = 32, Cn = 8, Ln = 4096, Kn = 128, Sn = 64;
constexpr int Wn = Ln - Sn + 1;          // 4033
constexpr int WT = 128;                  // windows per block
constexpr int NWT = (Wn + WT - 1) / WT;  // 32
constexpr int BDIM = 256;

__device__ __forceinline__ unsigned int f2bf(float f) {
  unsigned int u = __float_as_uint(f);
  u += 0x7FFFu + ((u >> 16) & 1u);       // round-to-nearest-even
  return u >> 16;
}

__global__ void init_out_kernel(unsigned int* out) {
  int i = blockIdx.x * blockDim.x + threadIdx.x;
  if (i < Bn * Kn) out[i] = 0x7F7FFFFFu;  // FLT_MAX bits
}

__launch_bounds__(BDIM, 2)
__global__ void med_kernel(const float* __restrict__ x,
                           const float* __restrict__ sh,
                           unsigned int* __restrict__ out) {
  constexpr int XRS = 200;  // Xr row stride (elems); 400B, 16B-aligned rows
  constexpr int BSS = 72;   // Bs row stride (elems); 144B, 16B-aligned rows
  __shared__ __align__(16) unsigned short Xr[8 * XRS];
  __shared__ __align__(16) unsigned short Bs[Kn * BSS];
  __shared__ float xnormC[Cn * WT];
  __shared__ float snormC[Cn * Kn];

  const int tid  = threadIdx.x;
  const int b    = blockIdx.y;
  const int w0   = blockIdx.x * WT;
  const int lane = tid & 63;
  const int wv   = tid >> 6;     // wave 0..3
  const int quad = lane >> 4;    // 0..3
  const int n16  = lane & 15;
  const int wbase = wv * 32;     // this wave's window offset in tile

  const float* xb = x + (size_t)b * Cn * Ln;

  // ---- per-block norms (all channels), fp32-exact ----
  {
    // xnorm: 256 threads = 8c x 32 groups, 4 windows each (rolling update)
    int c  = tid >> 5;
    int m0 = (tid & 31) * 4;
    const float* xc = xb + c * Ln;
    auto xq = [&](int i) -> float {
      float v = (i < Ln) ? xc[i] : 0.f;
      return v * v;
    };
    float s0 = 0.f;
    for (int s = 0; s < Sn; ++s) s0 += xq(w0 + m0 + s);
    float s1 = s0 - xq(w0 + m0 + 0) + xq(w0 + m0 + 64);
    float s2 = s1 - xq(w0 + m0 + 1) + xq(w0 + m0 + 65);
    float s3 = s2 - xq(w0 + m0 + 2) + xq(w0 + m0 + 66);
    xnormC[c * WT + m0 + 0] = s0;
    xnormC[c * WT + m0 + 1] = s1;
    xnormC[c * WT + m0 + 2] = s2;
    xnormC[c * WT + m0 + 3] = s3;
  }
  {
    // snorm: 1024 values, 4 per thread, float4 rows
    for (int rep = 0; rep < 4; ++rep) {
      int kid = tid + rep * BDIM;
      int c2 = kid >> 7, k = kid & 127;
      const float4* row = (const float4*)(sh + (size_t)(c2 * Kn + k) * Sn);
      float a = 0.f;
      #pragma unroll
      for (int i = 0; i < 16; ++i) {
        float4 v = row[i];
        a += v.x * v.x + v.y * v.y + v.z * v.z + v.w * v.w;
      }
      snormC[c2 * Kn + k] = a;
    }
  }

  float dist[2][8][4] = {};  // [mtile][ntile2][reg] summed distance over c

  for (int c = 0; c < Cn; ++c) {
    __syncthreads();  // protect LDS reuse (and first-iter norm writes)

    // ---- stage x: 8 shifted bf16 rows, zero-padded; 768 pairs ----
    {
      const float* xc = xb + c * Ln;
      #pragma unroll
      for (int rep = 0; rep < 3; ++rep) {
        int pid = tid + rep * BDIM;       // 0..767
        int r = pid / 96;
        int p = pid - r * 96;             // pair index 0..95 -> elems 2p,2p+1
        int i0 = w0 + r + 2 * p;
        float f0 = (i0 < Ln) ? xc[i0] : 0.f;
        float f1 = (i0 + 1 < Ln) ? xc[i0 + 1] : 0.f;
        *(unsigned int*)(&Xr[r * XRS + 2 * p]) = f2bf(f0) | (f2bf(f1) << 16);
      }
    }
    // ---- stage shapelets as -2*h bf16; 2048 float4 ----
    {
      const float4* shc = (const float4*)(sh + (size_t)c * Kn * Sn);
      #pragma unroll
      for (int rep = 0; rep < 8; ++rep) {
        int qid = tid + rep * BDIM;       // 0..2047
        int k = qid >> 4, sq = qid & 15;
        float4 v = shc[k * 16 + sq];
        unsigned int p0 = f2bf(-2.f * v.x) | (f2bf(-2.f * v.y) << 16);
        unsigned int p1 = f2bf(-2.f * v.z) | (f2bf(-2.f * v.w) << 16);
        *(uint2*)(&Bs[k * BSS + 4 * sq]) = make_uint2(p0, p1);
      }
    }
    __syncthreads();

    // xnorm for this wave's 32 windows (C/D row = quad*4+reg)
    float xn[2][4];
    #pragma unroll
    for (int mt = 0; mt < 2; ++mt)
      #pragma unroll
      for (int rg = 0; rg < 4; ++rg)
        xn[mt][rg] = xnormC[c * WT + wbase + mt * 16 + quad * 4 + rg];

    // A fragments: lane m = n16, k = quad*8+j (+ks*32); one aligned b128 each
    short8 af[2][2];
    #pragma unroll
    for (int mt = 0; mt < 2; ++mt)
      #pragma unroll
      for (int ks = 0; ks < 2; ++ks) {
        int i = wbase + mt * 16 + n16 + ks * 32 + quad * 8;
        af[mt][ks] = *(const short8*)(&Xr[(i & 7) * XRS + (i >> 3) * 8]);
      }

    #pragma unroll
    for (int pass = 0; pass < 2; ++pass) {
      short8 bfr[4][2];
      float sn[4];
      #pragma unroll
      for (int nt = 0; nt < 4; ++nt) {
        int ksh = pass * 64 + nt * 16 + n16;
        sn[nt] = snormC[c * Kn + ksh];
        #pragma unroll
        for (int ks = 0; ks < 2; ++ks)
          bfr[nt][ks] = *(const short8*)(&Bs[ksh * BSS + ks * 32 + quad * 8]);
      }
      #pragma unroll
      for (int mt = 0; mt < 2; ++mt)
        #pragma unroll
        for (int nt = 0; nt < 4; ++nt) {
          f32x4 acc;
          #pragma unroll
          for (int rg = 0; rg < 4; ++rg) acc[rg] = xn[mt][rg] + sn[nt];
          acc = __builtin_amdgcn_mfma_f32_16x16x32_bf16(af[mt][0], bfr[nt][0], acc, 0, 0, 0);
          acc = __builtin_amdgcn_mfma_f32_16x16x32_bf16(af[mt][1], bfr[nt][1], acc, 0, 0, 0);
          // acc == d2 (norms preloaded in C, -2 folded into B)
          #pragma unroll
          for (int rg = 0; rg < 4; ++rg)
            dist[mt][pass * 4 + nt][rg] += sqrtf(acc[rg]);
        }
    }
  }

  // ---- min over windows, then global combine ----
  const int wql = w0 + wbase + quad * 4;
  #pragma unroll
  for (int nt2 = 0; nt2 < 8; ++nt2) {
    float v = 3.4e38f;
    #pragma unroll
    for (int mt = 0; mt < 2; ++mt)
      #pragma unroll
      for (int rg = 0; rg < 4; ++rg) {
        int wg = wql + mt * 16 + rg;
        float d = (wg < Wn) ? dist[mt][nt2][rg] : 3.4e38f;
        v = fminf(v, d);
      }
    v = fminf(v, __shfl_xor(v, 16, 64));
    v = fminf(v, __shfl_xor(v, 32, 64));
    if (lane < 16)
      atomicMin(&out[b * Kn + nt2 * 16 + n16], __float_as_uint(v));
  }
}

extern "C" void kernel_launch(void* const* d_in, const int* in_sizes, int n_in,
                              void* d_out, int out_size, void* d_ws, size_t ws_size,
                              hipStream_t stream) {
  const float* x  = (const float*)d_in[0];
  const float* sh = (const float*)d_in[1];
  unsigned int* out = (unsigned int*)d_out;
  hipLaunchKernelGGL(init_out_kernel, dim3((Bn * Kn + 255) / 256), dim3(256), 0, stream, out);
  hipLaunchKernelGGL(med_kernel, dim3(NWT, Bn), dim3(BDIM), 0, stream, x, sh, out);
}

// Round 3
// 113.049 us; speedup vs baseline: 1.5819x; 1.5819x over previous
//
#include <hip/hip_runtime.h>

// MinEuclideanDistBlock: x(32,8,4096) f32, shapelets(8,128,64) f32 -> out(32,1,128) f32
// out[b,k] = min_w sum_c sqrt( xnorm[b,c,w] + snorm[c,k] - 2*sum_s x[b,c,w+s]*h[c,k,s] )
//
// R2 -> R3 changes (post-mortem: VALUBusy 60%, MfmaUtil 5% -> VALU-fat):
//  - sqrtf -> __builtin_amdgcn_sqrtf (raw v_sqrt_f32; OCML expansion was ~10 insts/cell).
//  - prep kernel pre-converts shapelets to bf16 (-2x folded) + snorm into d_ws;
//    med_kernel B-staging is now 4 uint4 global->LDS copies per c-iter (no f2bf),
//    and per-block snorm recompute (64 float4 + 256 FMA per thread) is gone.
//  - Bs LDS row stride 72 -> 80 elems (40 words = 8 mod 32): b128 writes 2-way (free),
//    reads <=4-way bank groups.

typedef short short8 __attribute__((ext_vector_type(8)));
typedef float f32x4 __attribute__((ext_vector_type(4)));

constexpr int Bn = 32, Cn = 8, Ln = 4096, Kn = 128, Sn = 64;
constexpr int Wn = Ln - Sn + 1;          // 4033
constexpr int WT = 128;                  // windows per block
constexpr int NWT = (Wn + WT - 1) / WT;  // 32
constexpr int BDIM = 256;

__device__ __forceinline__ unsigned int f2bf(float f) {
  unsigned int u = __float_as_uint(f);
  u += 0x7FFFu + ((u >> 16) & 1u);       // round-to-nearest-even
  return u >> 16;
}

// ws layout: [0, 128KB): ushort hbf[C][K][S] = bf16(-2*h);  [128KB, +4KB): float snorm[C][K]
__global__ void prep_kernel(const float* __restrict__ sh,
                            unsigned int* __restrict__ out,
                            unsigned short* __restrict__ hbf,
                            float* __restrict__ snorm) {
  int gid = blockIdx.x * blockDim.x + threadIdx.x;  // 0..4095
  out[gid] = 0x7F7FFFFFu;                           // FLT_MAX bits (Bn*Kn == 4096)
  if (gid < Cn * Kn) {
    const float4* row = (const float4*)(sh + (size_t)gid * Sn);
    uint2* orow = (uint2*)(hbf + (size_t)gid * Sn);
    float a = 0.f;
    #pragma unroll
    for (int i = 0; i < 16; ++i) {
      float4 v = row[i];
      a += v.x * v.x + v.y * v.y + v.z * v.z + v.w * v.w;
      unsigned int p0 = f2bf(-2.f * v.x) | (f2bf(-2.f * v.y) << 16);
      unsigned int p1 = f2bf(-2.f * v.z) | (f2bf(-2.f * v.w) << 16);
      orow[i] = make_uint2(p0, p1);
    }
    snorm[gid] = a;
  }
}

__launch_bounds__(BDIM, 2)
__global__ void med_kernel(const float* __restrict__ x,
                           const unsigned short* __restrict__ hbf,
                           const float* __restrict__ snorm,
                           unsigned int* __restrict__ out) {
  constexpr int XRS = 200;  // Xr row stride (elems); 400B, 16B-aligned rows
  constexpr int BSS = 80;   // Bs row stride (elems); 160B = 40 words (8 mod 32)
  __shared__ __align__(16) unsigned short Xr[8 * XRS];
  __shared__ __align__(16) unsigned short Bs[Kn * BSS];
  __shared__ __align__(16) float xnormC[Cn * WT];
  __shared__ __align__(16) float snormC[Cn * Kn];

  const int tid  = threadIdx.x;
  const int b    = blockIdx.y;
  const int w0   = blockIdx.x * WT;
  const int lane = tid & 63;
  const int wv   = tid >> 6;     // wave 0..3
  const int quad = lane >> 4;    // 0..3
  const int n16  = lane & 15;
  const int wbase = wv * 32;     // this wave's window offset in tile

  const float* xb = x + (size_t)b * Cn * Ln;

  // snorm: one float4 per thread from prep output
  ((float4*)snormC)[tid] = ((const float4*)snorm)[tid];

  // xnorm: 256 threads = 8c x 32 groups, 4 windows each (rolling update), fp32-exact
  {
    int c  = tid >> 5;
    int m0 = (tid & 31) * 4;
    const float* xc = xb + c * Ln;
    auto xq = [&](int i) -> float {
      float v = (i < Ln) ? xc[i] : 0.f;
      return v * v;
    };
    float s0 = 0.f;
    for (int s = 0; s < Sn; ++s) s0 += xq(w0 + m0 + s);
    float s1 = s0 - xq(w0 + m0 + 0) + xq(w0 + m0 + 64);
    float s2 = s1 - xq(w0 + m0 + 1) + xq(w0 + m0 + 65);
    float s3 = s2 - xq(w0 + m0 + 2) + xq(w0 + m0 + 66);
    xnormC[c * WT + m0 + 0] = s0;
    xnormC[c * WT + m0 + 1] = s1;
    xnormC[c * WT + m0 + 2] = s2;
    xnormC[c * WT + m0 + 3] = s3;
  }

  float dist[2][8][4] = {};  // [mtile][ntile2][reg] summed distance over c

  for (int c = 0; c < Cn; ++c) {
    __syncthreads();  // LDS reuse barrier (also covers first-iter norm writes)

    // ---- stage x: 8 shifted bf16 rows, zero-padded; 768 pairs ----
    {
      const float* xc = xb + c * Ln;
      #pragma unroll
      for (int rep = 0; rep < 3; ++rep) {
        int pid = tid + rep * BDIM;       // 0..767
        int r = pid / 96;
        int p = pid - r * 96;             // pair index 0..95 -> elems 2p,2p+1
        int i0 = w0 + r + 2 * p;
        float f0 = (i0 < Ln) ? xc[i0] : 0.f;
        float f1 = (i0 + 1 < Ln) ? xc[i0 + 1] : 0.f;
        *(unsigned int*)(&Xr[r * XRS + 2 * p]) = f2bf(f0) | (f2bf(f1) << 16);
      }
    }
    // ---- stage shapelets: pre-converted bf16, 1024 uint4 copies ----
    {
      const uint4* hb = (const uint4*)(hbf + (size_t)c * Kn * Sn);
      #pragma unroll
      for (int rep = 0; rep < 4; ++rep) {
        int qid = tid + rep * BDIM;       // 0..1023
        int k = qid >> 3, ch = qid & 7;   // 8 uint4 (of 8 elems) per k-row
        *(uint4*)(&Bs[k * BSS + ch * 8]) = hb[qid];
      }
    }
    __syncthreads();

    // xnorm for this wave's 32 windows (C/D row = quad*4+reg) — one b128 each
    float4 xn[2];
    #pragma unroll
    for (int mt = 0; mt < 2; ++mt)
      xn[mt] = *(const float4*)(&xnormC[c * WT + wbase + mt * 16 + quad * 4]);

    // A fragments: lane m = n16, k = quad*8+j (+ks*32); one aligned b128 each
    short8 af[2][2];
    #pragma unroll
    for (int mt = 0; mt < 2; ++mt)
      #pragma unroll
      for (int ks = 0; ks < 2; ++ks) {
        int i = wbase + mt * 16 + n16 + ks * 32 + quad * 8;
        af[mt][ks] = *(const short8*)(&Xr[(i & 7) * XRS + (i >> 3) * 8]);
      }

    #pragma unroll
    for (int pass = 0; pass < 2; ++pass) {
      short8 bfr[4][2];
      float sn[4];
      #pragma unroll
      for (int nt = 0; nt < 4; ++nt) {
        int ksh = pass * 64 + nt * 16 + n16;
        sn[nt] = snormC[c * Kn + ksh];
        #pragma unroll
        for (int ks = 0; ks < 2; ++ks)
          bfr[nt][ks] = *(const short8*)(&Bs[ksh * BSS + ks * 32 + quad * 8]);
      }
      #pragma unroll
      for (int mt = 0; mt < 2; ++mt)
        #pragma unroll
        for (int nt = 0; nt < 4; ++nt) {
          f32x4 acc;
          #pragma unroll
          for (int rg = 0; rg < 4; ++rg) acc[rg] = xn[mt][rg] + sn[nt];
          acc = __builtin_amdgcn_mfma_f32_16x16x32_bf16(af[mt][0], bfr[nt][0], acc, 0, 0, 0);
          acc = __builtin_amdgcn_mfma_f32_16x16x32_bf16(af[mt][1], bfr[nt][1], acc, 0, 0, 0);
          // acc == d2 (norms preloaded in C, -2 folded into B)
          #pragma unroll
          for (int rg = 0; rg < 4; ++rg)
            dist[mt][pass * 4 + nt][rg] += __builtin_amdgcn_sqrtf(acc[rg]);
        }
    }
  }

  // ---- min over windows, then global combine ----
  const int wql = w0 + wbase + quad * 4;
  #pragma unroll
  for (int nt2 = 0; nt2 < 8; ++nt2) {
    float v = 3.4e38f;
    #pragma unroll
    for (int mt = 0; mt < 2; ++mt)
      #pragma unroll
      for (int rg = 0; rg < 4; ++rg) {
        int wg = wql + mt * 16 + rg;
        float d = (wg < Wn) ? dist[mt][nt2][rg] : 3.4e38f;
        v = fminf(v, d);
      }
    v = fminf(v, __shfl_xor(v, 16, 64));
    v = fminf(v, __shfl_xor(v, 32, 64));
    if (lane < 16)
      atomicMin(&out[b * Kn + nt2 * 16 + n16], __float_as_uint(v));
  }
}

extern "C" void kernel_launch(void* const* d_in, const int* in_sizes, int n_in,
                              void* d_out, int out_size, void* d_ws, size_t ws_size,
                              hipStream_t stream) {
  const float* x  = (const float*)d_in[0];
  const float* sh = (const float*)d_in[1];
  unsigned int* out = (unsigned int*)d_out;
  unsigned short* hbf = (unsigned short*)d_ws;                  // 128 KB
  float* snorm = (float*)((char*)d_ws + (size_t)Cn * Kn * Sn * 2);  // +4 KB
  hipLaunchKernelGGL(prep_kernel, dim3(16), dim3(256), 0, stream, sh, out, hbf, snorm);
  hipLaunchKernelGGL(med_kernel, dim3(NWT, Bn), dim3(BDIM), 0, stream, x, hbf, snorm, out);
}